// Round 2
// baseline (548.335 us; speedup 1.0000x reference)
//
#include <hip/hip_runtime.h>

#define EPS 1e-5f
#define SLOPE 0.2f

// Exact two-pass LayerNorm + LeakyReLU over N register-resident elements.
template<int N>
__device__ __forceinline__ void ln_lrelu(float* h, const float* __restrict__ g,
                                         const float* __restrict__ b) {
  float m = 0.f;
#pragma unroll
  for (int j = 0; j < N; ++j) m += h[j];
  m *= (1.0f / N);
  float v = 0.f;
#pragma unroll
  for (int j = 0; j < N; ++j) { float d = h[j] - m; v = fmaf(d, d, v); }
  v *= (1.0f / N);
  float rs = rsqrtf(v + EPS);
#pragma unroll
  for (int j = 0; j < N; ++j) {
    float t = (h[j] - m) * rs * g[j] + b[j];
    h[j] = t > 0.f ? t : SLOPE * t;
  }
}

template<int DIN, int DOUT>
__device__ __forceinline__ void linear(const float* hin, float* hout,
                                       const float* __restrict__ W) {
#pragma unroll
  for (int j = 0; j < DOUT; ++j) hout[j] = 0.f;
#pragma unroll
  for (int k = 0; k < DIN; ++k) {
    float hk = hin[k];
#pragma unroll
    for (int j = 0; j < DOUT; ++j) hout[j] = fmaf(hk, W[k * DOUT + j], hout[j]);
  }
}

__global__ __launch_bounds__(256, 6) void disc_fused(
    const float* __restrict__ x,
    const float* __restrict__ W1, const float* __restrict__ g1, const float* __restrict__ b1,
    const float* __restrict__ W2, const float* __restrict__ g2, const float* __restrict__ b2,
    const float* __restrict__ W3, const float* __restrict__ g3, const float* __restrict__ b3,
    const float* __restrict__ W4, const float* __restrict__ g4, const float* __restrict__ b4,
    const float* __restrict__ W5, const float* __restrict__ g5, const float* __restrict__ b5,
    const float* __restrict__ W6, const float* __restrict__ g6, const float* __restrict__ b6,
    const float* __restrict__ W7, const float* __restrict__ g7, const float* __restrict__ b7,
    const float* __restrict__ W8, const float* __restrict__ b8,
    float* __restrict__ out, int nrows) {
  // Per-WAVE x staging: wave w owns xs[w] (64 rows x 16-col chunk, stride 20
  // floats -> b128 read/write spread uniformly over all 32 banks). No
  // __syncthreads anywhere: producer and consumer are the same wave, and DS
  // ops within a wave execute in program order.
  __shared__ float xs[4][64][20];
  const int t = threadIdx.x;
  const int w = t >> 6, l = t & 63;
  const long nmax = (long)nrows - 1;
  const long wrow0 = (long)blockIdx.x * 256 + (long)w * 64;  // wave's first row
  const long row = wrow0 + l;                                // this thread's row

  float h1[32];
#pragma unroll
  for (int j = 0; j < 32; ++j) h1[j] = 0.f;

  const float4* __restrict__ x4 = reinterpret_cast<const float4*>(x);
  for (int c = 0; c < 8; ++c) {  // 8 chunks of 16 columns
    // stage this wave's 64x16 sub-tile: 256 float4, 4 per lane, coalesced 64B
#pragma unroll
    for (int q = 0; q < 4; ++q) {
      int idx = q * 64 + l;          // 0..255
      int r = idx >> 2, cu = idx & 3;
      long rr = wrow0 + r; if (rr > nmax) rr = nmax;
      float4 v = x4[rr * 32 + c * 4 + cu];
      *reinterpret_cast<float4*>(&xs[w][r][cu * 4]) = v;
    }
    // consume own row (lane l -> row l), weights wave-uniform -> s_load
#pragma unroll
    for (int k4 = 0; k4 < 4; ++k4) {
      float4 xv = *reinterpret_cast<const float4*>(&xs[w][l][k4 * 4]);
#pragma unroll
      for (int kk = 0; kk < 4; ++kk) {
        float xk = (kk == 0) ? xv.x : (kk == 1) ? xv.y : (kk == 2) ? xv.z : xv.w;
        const float* __restrict__ wr = &W1[(c * 16 + k4 * 4 + kk) * 32];
#pragma unroll
        for (int j = 0; j < 32; ++j) h1[j] = fmaf(xk, wr[j], h1[j]);
      }
    }
  }
  ln_lrelu<32>(h1, g1, b1);

  // ---- Layer 2 (32->64) streamed so h2[64] is never register-resident ----
  // Pass 1: LN stats via E[x^2]-m^2 (safe: EPS floors the variance).
  float sum2 = 0.f, sq2 = 0.f;
  for (int jb = 0; jb < 16; ++jb) {  // rolled; 4 outputs per block
    float a0 = 0.f, a1 = 0.f, a2 = 0.f, a3 = 0.f;
#pragma unroll
    for (int k = 0; k < 32; ++k) {
      const float* __restrict__ wr = &W2[k * 64 + jb * 4];
      a0 = fmaf(h1[k], wr[0], a0);
      a1 = fmaf(h1[k], wr[1], a1);
      a2 = fmaf(h1[k], wr[2], a2);
      a3 = fmaf(h1[k], wr[3], a3);
    }
    sum2 += a0 + a1 + a2 + a3;
    sq2 = fmaf(a0, a0, sq2); sq2 = fmaf(a1, a1, sq2);
    sq2 = fmaf(a2, a2, sq2); sq2 = fmaf(a3, a3, sq2);
  }
  const float m2 = sum2 * (1.0f / 64.0f);
  const float v2 = fmaf(-m2, m2, sq2 * (1.0f / 64.0f));
  const float rs2 = rsqrtf(v2 + EPS);

  // Pass 2: recompute h2 block, normalize+LeakyReLU, fuse into h3 accumulation.
  float h3[32];
#pragma unroll
  for (int i = 0; i < 32; ++i) h3[i] = 0.f;
  for (int jb = 0; jb < 16; ++jb) {
    float a0 = 0.f, a1 = 0.f, a2 = 0.f, a3 = 0.f;
#pragma unroll
    for (int k = 0; k < 32; ++k) {
      const float* __restrict__ wr = &W2[k * 64 + jb * 4];
      a0 = fmaf(h1[k], wr[0], a0);
      a1 = fmaf(h1[k], wr[1], a1);
      a2 = fmaf(h1[k], wr[2], a2);
      a3 = fmaf(h1[k], wr[3], a3);
    }
#pragma unroll
    for (int u = 0; u < 4; ++u) {
      float a = (u == 0) ? a0 : (u == 1) ? a1 : (u == 2) ? a2 : a3;
      int j = jb * 4 + u;
      float y = (a - m2) * rs2 * g2[j] + b2[j];
      y = y > 0.f ? y : SLOPE * y;
      const float* __restrict__ wr3 = &W3[j * 32];
#pragma unroll
      for (int i = 0; i < 32; ++i) h3[i] = fmaf(y, wr3[i], h3[i]);
    }
  }
  ln_lrelu<32>(h3, g3, b3);

  float h4[16]; linear<32, 16>(h3, h4, W4); ln_lrelu<16>(h4, g4, b4);
  float h5[8];  linear<16, 8>(h4, h5, W5);  ln_lrelu<8>(h5, g5, b5);
  float h6[4];  linear<8, 4>(h5, h6, W6);   ln_lrelu<4>(h6, g6, b6);
  float h7[2];  linear<4, 2>(h6, h7, W7);   ln_lrelu<2>(h7, g7, b7);

  float o = fmaf(h7[1], W8[1], fmaf(h7[0], W8[0], b8[0]));
  if (row < (long)nrows) out[row] = o;
}

extern "C" void kernel_launch(void* const* d_in, const int* in_sizes, int n_in,
                              void* d_out, int out_size, void* d_ws, size_t ws_size,
                              hipStream_t stream) {
  const float* x  = (const float*)d_in[0];
  const float* W1 = (const float*)d_in[1];
  const float* g1 = (const float*)d_in[2];
  const float* b1 = (const float*)d_in[3];
  const float* W2 = (const float*)d_in[4];
  const float* g2 = (const float*)d_in[5];
  const float* b2 = (const float*)d_in[6];
  const float* W3 = (const float*)d_in[7];
  const float* g3 = (const float*)d_in[8];
  const float* b3 = (const float*)d_in[9];
  const float* W4 = (const float*)d_in[10];
  const float* g4 = (const float*)d_in[11];
  const float* b4 = (const float*)d_in[12];
  const float* W5 = (const float*)d_in[13];
  const float* g5 = (const float*)d_in[14];
  const float* b5 = (const float*)d_in[15];
  const float* W6 = (const float*)d_in[16];
  const float* g6 = (const float*)d_in[17];
  const float* b6 = (const float*)d_in[18];
  const float* W7 = (const float*)d_in[19];
  const float* g7 = (const float*)d_in[20];
  const float* b7 = (const float*)d_in[21];
  const float* W8 = (const float*)d_in[22];
  const float* b8 = (const float*)d_in[23];
  float* out = (float*)d_out;

  const int nrows = in_sizes[0] / 128;          // 524288
  const int grid = (nrows + 255) / 256;         // 2048 blocks x 4 waves
  hipLaunchKernelGGL(disc_fused, dim3(grid), dim3(256), 0, stream,
                     x, W1, g1, b1, W2, g2, b2, W3, g3, b3, W4, g4, b4,
                     W5, g5, b5, W6, g6, b6, W7, g7, b7, W8, b8, out, nrows);
}

// Round 3
// 177.326 us; speedup vs baseline: 3.0922x; 3.0922x over previous
//
#include <hip/hip_runtime.h>

#define EPS 1e-5f
#define SLOPE 0.2f

// Pairwise-tree sum of N register-resident floats (short dep chains).
template<int N>
__device__ __forceinline__ float tree_sum(const float* h) {
  float t[N];
#pragma unroll
  for (int j = 0; j < N; ++j) t[j] = h[j];
#pragma unroll
  for (int s = N / 2; s > 0; s >>= 1)
#pragma unroll
    for (int j = 0; j < s; ++j) t[j] += t[j + s];
  return t[0];
}

// Exact LayerNorm + LeakyReLU over N register-resident elements.
template<int N>
__device__ __forceinline__ void ln_lrelu(float* h, const float* __restrict__ g,
                                         const float* __restrict__ b) {
  float m = tree_sum<N>(h) * (1.0f / N);
  float d[N];
#pragma unroll
  for (int j = 0; j < N; ++j) { float e = h[j] - m; d[j] = e * e; }
  float v = tree_sum<N>(d) * (1.0f / N);
  float rs = rsqrtf(v + EPS);
#pragma unroll
  for (int j = 0; j < N; ++j) {
    float t = (h[j] - m) * rs * g[j] + b[j];
    h[j] = t > 0.f ? t : SLOPE * t;
  }
}

template<int DIN, int DOUT>
__device__ __forceinline__ void linear(const float* hin, float* hout,
                                       const float* __restrict__ W) {
#pragma unroll
  for (int j = 0; j < DOUT; ++j) hout[j] = 0.f;
#pragma unroll
  for (int k = 0; k < DIN; ++k) {
    float hk = hin[k];
#pragma unroll
    for (int j = 0; j < DOUT; ++j) hout[j] = fmaf(hk, W[k * DOUT + j], hout[j]);
  }
}

__global__ __launch_bounds__(256) void disc_fused(
    const float* __restrict__ x,
    const float* __restrict__ W1, const float* __restrict__ g1, const float* __restrict__ b1,
    const float* __restrict__ W2, const float* __restrict__ g2, const float* __restrict__ b2,
    const float* __restrict__ W3, const float* __restrict__ g3, const float* __restrict__ b3,
    const float* __restrict__ W4, const float* __restrict__ g4, const float* __restrict__ b4,
    const float* __restrict__ W5, const float* __restrict__ g5, const float* __restrict__ b5,
    const float* __restrict__ W6, const float* __restrict__ g6, const float* __restrict__ b6,
    const float* __restrict__ W7, const float* __restrict__ g7, const float* __restrict__ b7,
    const float* __restrict__ W8, const float* __restrict__ b8,
    float* __restrict__ out, int nrows) {
  const long row = (long)blockIdx.x * 256 + threadIdx.x;
  if (row >= (long)nrows) return;

  // ---- Layer 1 (128->32): direct per-thread row loads, no LDS, no barriers.
  // Each thread reads its own contiguous 512B row as 32 float4; the 4 loads
  // touching each 128B line are consecutive -> L1/MSHR merges, HBM sees 268MB.
  const float4* __restrict__ xr4 = reinterpret_cast<const float4*>(x) + row * 32;
  float h1[32];
#pragma unroll
  for (int j = 0; j < 32; ++j) h1[j] = 0.f;

#pragma unroll 1           // keep only one 8-load burst (32 VGPR) in flight
  for (int cc = 0; cc < 4; ++cc) {
    float4 bv[8];
#pragma unroll
    for (int q = 0; q < 8; ++q) bv[q] = xr4[cc * 8 + q];
#pragma unroll
    for (int q = 0; q < 8; ++q) {
#pragma unroll
      for (int kk = 0; kk < 4; ++kk) {
        float xk = (kk == 0) ? bv[q].x : (kk == 1) ? bv[q].y
                 : (kk == 2) ? bv[q].z : bv[q].w;
        const float* __restrict__ wr = &W1[(cc * 32 + q * 4 + kk) * 32];
#pragma unroll
        for (int j = 0; j < 32; ++j) h1[j] = fmaf(xk, wr[j], h1[j]);
      }
    }
  }
  ln_lrelu<32>(h1, g1, b1);

  // ---- Layer 2 (32->64) streamed: h2 never register-resident. ----
  // Pass 1: LN stats via E[x^2]-m^2 (EPS floors the variance -> safe).
  float sum2 = 0.f, sq2 = 0.f;
#pragma unroll 1
  for (int jb = 0; jb < 16; ++jb) {
    float a0 = 0.f, a1 = 0.f, a2 = 0.f, a3 = 0.f;
#pragma unroll
    for (int k = 0; k < 32; ++k) {
      const float* __restrict__ wr = &W2[k * 64 + jb * 4];
      a0 = fmaf(h1[k], wr[0], a0);
      a1 = fmaf(h1[k], wr[1], a1);
      a2 = fmaf(h1[k], wr[2], a2);
      a3 = fmaf(h1[k], wr[3], a3);
    }
    sum2 += (a0 + a1) + (a2 + a3);
    sq2 = fmaf(a0, a0, sq2); sq2 = fmaf(a1, a1, sq2);
    sq2 = fmaf(a2, a2, sq2); sq2 = fmaf(a3, a3, sq2);
  }
  const float m2 = sum2 * (1.0f / 64.0f);
  const float v2 = fmaf(-m2, m2, sq2 * (1.0f / 64.0f));
  const float rs2 = rsqrtf(v2 + EPS);

  // Pass 2: recompute h2 block, LN+LeakyReLU, fuse straight into h3 accum.
  float h3[32];
#pragma unroll
  for (int i = 0; i < 32; ++i) h3[i] = 0.f;
#pragma unroll 1
  for (int jb = 0; jb < 16; ++jb) {
    float a0 = 0.f, a1 = 0.f, a2 = 0.f, a3 = 0.f;
#pragma unroll
    for (int k = 0; k < 32; ++k) {
      const float* __restrict__ wr = &W2[k * 64 + jb * 4];
      a0 = fmaf(h1[k], wr[0], a0);
      a1 = fmaf(h1[k], wr[1], a1);
      a2 = fmaf(h1[k], wr[2], a2);
      a3 = fmaf(h1[k], wr[3], a3);
    }
#pragma unroll
    for (int u = 0; u < 4; ++u) {
      float a = (u == 0) ? a0 : (u == 1) ? a1 : (u == 2) ? a2 : a3;
      int j = jb * 4 + u;
      float y = (a - m2) * rs2 * g2[j] + b2[j];
      y = y > 0.f ? y : SLOPE * y;
      const float* __restrict__ wr3 = &W3[j * 32];
#pragma unroll
      for (int i = 0; i < 32; ++i) h3[i] = fmaf(y, wr3[i], h3[i]);
    }
  }
  ln_lrelu<32>(h3, g3, b3);

  float h4[16]; linear<32, 16>(h3, h4, W4); ln_lrelu<16>(h4, g4, b4);
  float h5[8];  linear<16, 8>(h4, h5, W5);  ln_lrelu<8>(h5, g5, b5);
  float h6[4];  linear<8, 4>(h5, h6, W6);   ln_lrelu<4>(h6, g6, b6);
  float h7[2];  linear<4, 2>(h6, h7, W7);   ln_lrelu<2>(h7, g7, b7);

  out[row] = fmaf(h7[1], W8[1], fmaf(h7[0], W8[0], b8[0]));
}

extern "C" void kernel_launch(void* const* d_in, const int* in_sizes, int n_in,
                              void* d_out, int out_size, void* d_ws, size_t ws_size,
                              hipStream_t stream) {
  const float* x  = (const float*)d_in[0];
  const float* W1 = (const float*)d_in[1];
  const float* g1 = (const float*)d_in[2];
  const float* b1 = (const float*)d_in[3];
  const float* W2 = (const float*)d_in[4];
  const float* g2 = (const float*)d_in[5];
  const float* b2 = (const float*)d_in[6];
  const float* W3 = (const float*)d_in[7];
  const float* g3 = (const float*)d_in[8];
  const float* b3 = (const float*)d_in[9];
  const float* W4 = (const float*)d_in[10];
  const float* g4 = (const float*)d_in[11];
  const float* b4 = (const float*)d_in[12];
  const float* W5 = (const float*)d_in[13];
  const float* g5 = (const float*)d_in[14];
  const float* b5 = (const float*)d_in[15];
  const float* W6 = (const float*)d_in[16];
  const float* g6 = (const float*)d_in[17];
  const float* b6 = (const float*)d_in[18];
  const float* W7 = (const float*)d_in[19];
  const float* g7 = (const float*)d_in[20];
  const float* b7 = (const float*)d_in[21];
  const float* W8 = (const float*)d_in[22];
  const float* b8 = (const float*)d_in[23];
  float* out = (float*)d_out;

  const int nrows = in_sizes[0] / 128;          // 524288
  const int grid = (nrows + 255) / 256;         // 2048
  hipLaunchKernelGGL(disc_fused, dim3(grid), dim3(256), 0, stream,
                     x, W1, g1, b1, W2, g2, b2, W3, g3, b3, W4, g4, b4,
                     W5, g5, b5, W6, g6, b6, W7, g7, b7, W8, b8, out, nrows);
}